// Round 1
// baseline (1594.763 us; speedup 1.0000x reference)
//
#include <hip/hip_runtime.h>
#include <stdint.h>

#define ROWS   16384   // B*S
#define KDIM   256
#define DMDIM  512
#define DOUTD  1024
#define BANKN  4096
#define DIND   1024
#define HDIMD  2048

// ---------------- generic fp32 GEMM, 128x128 tile, 8x8 per thread ----------------
template<bool RELU, bool BIAS>
__global__ __launch_bounds__(256)
void gemm128(const float* __restrict__ A, const float* __restrict__ Bm,
             const float* __restrict__ bias, float* __restrict__ C,
             int M, int N, int K)
{
    __shared__ float As[16][132];
    __shared__ float Bs[16][132];
    const int tid = threadIdx.x;
    const int tx = tid & 15, ty = tid >> 4;
    const int m0 = blockIdx.y * 128;
    const int n0 = blockIdx.x * 128;
    const int r0 = ty * 4;
    const int c0 = tx * 4;
    float acc[8][8];
    #pragma unroll
    for (int i = 0; i < 8; i++)
        #pragma unroll
        for (int j = 0; j < 8; j++) acc[i][j] = 0.f;

    for (int kt = 0; kt < K; kt += 16) {
        #pragma unroll
        for (int l = 0; l < 2; l++) {
            int id = tid + l * 256;
            int m = id >> 2, kq = id & 3;
            float4 av = *(const float4*)(A + (size_t)(m0 + m) * K + kt + kq * 4);
            As[kq * 4 + 0][m] = av.x;
            As[kq * 4 + 1][m] = av.y;
            As[kq * 4 + 2][m] = av.z;
            As[kq * 4 + 3][m] = av.w;
        }
        #pragma unroll
        for (int l = 0; l < 2; l++) {
            int id = tid + l * 256;
            int n4 = id & 31, kk = id >> 5;
            float4 bv = *(const float4*)(Bm + (size_t)(kt + kk) * N + n0 + n4 * 4);
            *(float4*)&Bs[kk][n4 * 4] = bv;
        }
        __syncthreads();
        #pragma unroll
        for (int k = 0; k < 16; k++) {
            float4 a0 = *(const float4*)&As[k][r0];
            float4 a1 = *(const float4*)&As[k][r0 + 64];
            float4 b0 = *(const float4*)&Bs[k][c0];
            float4 b1 = *(const float4*)&Bs[k][c0 + 64];
            float a[8] = {a0.x, a0.y, a0.z, a0.w, a1.x, a1.y, a1.z, a1.w};
            float b[8] = {b0.x, b0.y, b0.z, b0.w, b1.x, b1.y, b1.z, b1.w};
            #pragma unroll
            for (int i = 0; i < 8; i++)
                #pragma unroll
                for (int j = 0; j < 8; j++)
                    acc[i][j] = fmaf(a[i], b[j], acc[i][j]);
        }
        __syncthreads();
    }
    float4 bia0 = make_float4(0.f,0.f,0.f,0.f), bia1 = bia0;
    if (BIAS) {
        bia0 = *(const float4*)(bias + n0 + c0);
        bia1 = *(const float4*)(bias + n0 + c0 + 64);
    }
    #pragma unroll
    for (int i = 0; i < 8; i++) {
        int m = m0 + ((i < 4) ? (r0 + i) : (r0 + 64 + i - 4));
        float o[8];
        #pragma unroll
        for (int j = 0; j < 8; j++) o[j] = acc[i][j];
        o[0]+=bia0.x; o[1]+=bia0.y; o[2]+=bia0.z; o[3]+=bia0.w;
        o[4]+=bia1.x; o[5]+=bia1.y; o[6]+=bia1.z; o[7]+=bia1.w;
        if (RELU) {
            #pragma unroll
            for (int j = 0; j < 8; j++) o[j] = fmaxf(o[j], 0.f);
        }
        *(float4*)(C + (size_t)m * N + n0 + c0)      = make_float4(o[0],o[1],o[2],o[3]);
        *(float4*)(C + (size_t)m * N + n0 + c0 + 64) = make_float4(o[4],o[5],o[6],o[7]);
    }
}

// ---------------- generic fp32 GEMM, 64x64 tile, 4x4 per thread, optional B^T + split-K ----------------
template<bool BT, bool BIAS>
__global__ __launch_bounds__(256)
void gemm64(const float* __restrict__ A, const float* __restrict__ Bm,
            const float* __restrict__ bias, float* __restrict__ C,
            int M, int N, int K, int kLen)
{
    __shared__ float As[16][68];
    __shared__ float Bs[16][68];
    const int tid = threadIdx.x;
    const int tx = tid & 15, ty = tid >> 4;
    const int m0 = blockIdx.y * 64;
    const int n0 = blockIdx.x * 64;
    const int z  = blockIdx.z;
    const int kStart = z * kLen;
    float* Cz = C + (size_t)z * M * N;
    float acc[4][4];
    #pragma unroll
    for (int i = 0; i < 4; i++)
        #pragma unroll
        for (int j = 0; j < 4; j++) acc[i][j] = 0.f;

    for (int kt = kStart; kt < kStart + kLen; kt += 16) {
        {
            int m = tid >> 2, kq = tid & 3;
            float4 av = *(const float4*)(A + (size_t)(m0 + m) * K + kt + kq * 4);
            As[kq*4+0][m]=av.x; As[kq*4+1][m]=av.y; As[kq*4+2][m]=av.z; As[kq*4+3][m]=av.w;
        }
        if (BT) {
            int n = tid >> 2, kq = tid & 3;
            float4 bv = *(const float4*)(Bm + (size_t)(n0 + n) * K + kt + kq * 4);
            Bs[kq*4+0][n]=bv.x; Bs[kq*4+1][n]=bv.y; Bs[kq*4+2][n]=bv.z; Bs[kq*4+3][n]=bv.w;
        } else {
            int n4 = tid & 15, kk = tid >> 4;
            float4 bv = *(const float4*)(Bm + (size_t)(kt + kk) * N + n0 + n4 * 4);
            *(float4*)&Bs[kk][n4 * 4] = bv;
        }
        __syncthreads();
        #pragma unroll
        for (int k = 0; k < 16; k++) {
            float4 a0 = *(const float4*)&As[k][ty * 4];
            float4 b0 = *(const float4*)&Bs[k][tx * 4];
            float a[4] = {a0.x, a0.y, a0.z, a0.w};
            float b[4] = {b0.x, b0.y, b0.z, b0.w};
            #pragma unroll
            for (int i = 0; i < 4; i++)
                #pragma unroll
                for (int j = 0; j < 4; j++)
                    acc[i][j] = fmaf(a[i], b[j], acc[i][j]);
        }
        __syncthreads();
    }
    float4 bi = make_float4(0.f,0.f,0.f,0.f);
    if (BIAS) bi = *(const float4*)(bias + n0 + tx * 4);
    #pragma unroll
    for (int i = 0; i < 4; i++) {
        int m = m0 + ty * 4 + i;
        *(float4*)(Cz + (size_t)m * N + n0 + tx * 4) =
            make_float4(acc[i][0]+bi.x, acc[i][1]+bi.y, acc[i][2]+bi.z, acc[i][3]+bi.w);
    }
}

// ---------------- 1/max(||bank_keys[n]||,1e-12) ----------------
__global__ __launch_bounds__(64)
void invkn_k(const float* __restrict__ keys, float* __restrict__ inv_kn)
{
    int n = blockIdx.x, l = threadIdx.x;
    const float4* r = (const float4*)(keys + (size_t)n * 512);
    float4 a = r[l], b = r[l + 64];
    float s = a.x*a.x + a.y*a.y + a.z*a.z + a.w*a.w
            + b.x*b.x + b.y*b.y + b.z*b.z + b.w*b.w;
    #pragma unroll
    for (int off = 32; off; off >>= 1) s += __shfl_xor(s, off);
    if (l == 0) inv_kn[n] = 1.0f / fmaxf(sqrtf(s), 1e-12f);
}

// ---------------- masked scaled softmax over 4096 slots, per k-row, in place ----------------
__global__ __launch_bounds__(256)
void softmax_k(const float* __restrict__ Mw, const float* __restrict__ inv_kn,
               const float* __restrict__ used, float* __restrict__ sc)
{
    const int k = blockIdx.x, tid = threadIdx.x;
    __shared__ float red[256];
    float m0 = Mw[(size_t)k*512 + tid];
    float m1 = Mw[(size_t)k*512 + 256 + tid];
    red[tid] = m0*m0 + m1*m1;
    __syncthreads();
    for (int s = 128; s > 0; s >>= 1) { if (tid < s) red[tid] += red[tid+s]; __syncthreads(); }
    float scale = 4.0f / fmaxf(sqrtf(red[0]), 1e-12f);
    __syncthreads();
    float vals[16];
    float mx = -3.0e38f;
    #pragma unroll
    for (int j = 0; j < 16; j++) {
        int n = j*256 + tid;
        float v = sc[(size_t)k*4096 + n] * scale * inv_kn[n];
        v = (used[n] > 0.5f) ? v : -1e30f;
        vals[j] = v; mx = fmaxf(mx, v);
    }
    red[tid] = mx; __syncthreads();
    for (int s = 128; s > 0; s >>= 1) { if (tid < s) red[tid] = fmaxf(red[tid], red[tid+s]); __syncthreads(); }
    mx = red[0]; __syncthreads();
    float sum = 0.f;
    #pragma unroll
    for (int j = 0; j < 16; j++) { float e = expf(vals[j] - mx); vals[j] = e; sum += e; }
    red[tid] = sum; __syncthreads();
    for (int s = 128; s > 0; s >>= 1) { if (tid < s) red[tid] += red[tid+s]; __syncthreads(); }
    float inv = 1.0f / red[0];
    #pragma unroll
    for (int j = 0; j < 16; j++) { int n = j*256 + tid; sc[(size_t)k*4096 + n] = vals[j] * inv; }
}

// ---------------- reduce split-K partials ----------------
__global__ __launch_bounds__(256)
void redk_k(const float* __restrict__ part, float* __restrict__ outp)
{
    int idx = blockIdx.x * 256 + threadIdx.x;   // 131072 total
    float s = 0.f;
    #pragma unroll
    for (int z = 0; z < 8; z++) s += part[(size_t)z * 131072 + idx];
    outp[idx] = s;
}

// ---------------- rn table: RMS-norm of (M[k] + bank_out[k]) ----------------
__global__ __launch_bounds__(256)
void rn_k(const float* __restrict__ Mw, const float* __restrict__ banko,
          const float* __restrict__ g, float* __restrict__ rn)
{
    int k = blockIdx.x, tid = threadIdx.x;
    __shared__ float red[256];
    float r0 = Mw[(size_t)k*512 + tid]       + banko[(size_t)k*512 + tid];
    float r1 = Mw[(size_t)k*512 + 256 + tid] + banko[(size_t)k*512 + 256 + tid];
    red[tid] = r0*r0 + r1*r1;
    __syncthreads();
    for (int s = 128; s > 0; s >>= 1) { if (tid < s) red[tid] += red[tid+s]; __syncthreads(); }
    float denom = sqrtf(red[0] * (1.0f/512.0f) + 1e-6f);
    rn[(size_t)k*512 + tid]       = r0 * (g[tid] / denom);
    rn[(size_t)k*512 + 256 + tid] = r1 * (g[256 + tid] / denom);
}

// ---------------- per-row argmax (first-index ties) + sticky 256-bit mask ----------------
__global__ __launch_bounds__(64)
void topmask_k(const float* __restrict__ logits, unsigned long long* __restrict__ masks,
               int* __restrict__ cArr)
{
    int row = blockIdx.x, l = threadIdx.x;
    const float* lg = logits + (size_t)row * 256;
    float v0 = lg[l], v1 = lg[64 + l], v2 = lg[128 + l], v3 = lg[192 + l];
    float bv = v0; int bp = l;
    if (v1 > bv) { bv = v1; bp = 64 + l; }
    if (v2 > bv) { bv = v2; bp = 128 + l; }
    if (v3 > bv) { bv = v3; bp = 192 + l; }
    #pragma unroll
    for (int off = 32; off; off >>= 1) {
        float ov = __shfl_xor(bv, off);
        int   op = __shfl_xor(bp, off);
        if (ov > bv || (ov == bv && op < bp)) { bv = ov; bp = op; }
    }
    // sticky(p): lg[p]+0.1 beats the max (with argmax-first-index tie rule)
    float t0 = v0 + 0.1f, t1 = v1 + 0.1f, t2 = v2 + 0.1f, t3 = v3 + 0.1f;
    unsigned long long w0 = __ballot((t0 > bv) || (t0 == bv && (l)       < bp));
    unsigned long long w1 = __ballot((t1 > bv) || (t1 == bv && (64 + l)  < bp));
    unsigned long long w2 = __ballot((t2 > bv) || (t2 == bv && (128 + l) < bp));
    unsigned long long w3 = __ballot((t3 > bv) || (t3 == bv && (192 + l) < bp));
    if (l == 0) {
        masks[(size_t)row*4 + 0] = w0;
        masks[(size_t)row*4 + 1] = w1;
        masks[(size_t)row*4 + 2] = w2;
        masks[(size_t)row*4 + 3] = w3;
        cArr[row] = bp;
    }
}

// ---------------- sequential mode scan (8 independent chains, lane per batch) ----------------
__global__ __launch_bounds__(64)
void scan_k(const unsigned long long* __restrict__ masks, const int* __restrict__ cArr,
            int* __restrict__ mode_idx)
{
    int b = threadIdx.x;
    if (b >= 8) return;
    const unsigned long long* mp = masks + (size_t)b * 2048 * 4;
    const int* cp = cArr + b * 2048;
    int* op = mode_idx + b * 2048;
    int prev = 0;   // prev_mode one-hot at index 0
    for (int t = 0; t < 2048; t++) {
        unsigned long long w0 = mp[(size_t)t*4+0], w1 = mp[(size_t)t*4+1];
        unsigned long long w2 = mp[(size_t)t*4+2], w3 = mp[(size_t)t*4+3];
        int c = cp[t];
        unsigned long long wlo = (prev & 64) ? w1 : w0;
        unsigned long long whi = (prev & 64) ? w3 : w2;
        unsigned long long w   = (prev & 128) ? whi : wlo;
        int stick = (int)((w >> (prev & 63)) & 1ull);
        prev = stick ? prev : c;
        op[t] = prev;
    }
}

// ---------------- modes one-hot output ----------------
__global__ __launch_bounds__(64)
void modesw_k(const int* __restrict__ mode_idx, float* __restrict__ modes)
{
    int r = blockIdx.x, l = threadIdx.x;
    int k = mode_idx[r];
    int base = l * 4;
    float4 v = make_float4(base == k ? 1.f : 0.f, base+1 == k ? 1.f : 0.f,
                           base+2 == k ? 1.f : 0.f, base+3 == k ? 1.f : 0.f);
    ((float4*)(modes + (size_t)r * 256))[l] = v;
}

// ---------------- y gather from 256-entry table ----------------
__global__ __launch_bounds__(256)
void ygather_k(const int* __restrict__ mode_idx, const float* __restrict__ ytab,
               float* __restrict__ y)
{
    int r = blockIdx.x;
    int k = mode_idx[r];
    const float4* src = (const float4*)(ytab + (size_t)k * 1024);
    float4* dst = (float4*)(y + (size_t)r * 1024);
    dst[threadIdx.x] = src[threadIdx.x];
}

extern "C" void kernel_launch(void* const* d_in, const int* in_sizes, int n_in,
                              void* d_out, int out_size, void* d_ws, size_t ws_size,
                              hipStream_t stream)
{
    const float* x       = (const float*)d_in[0];
    // d_in[1] = prev_mode: one-hot at 0 (handled as prev index 0 in scan_k)
    const float* Wtr_w   = (const float*)d_in[2];
    const float* Wtr_b   = (const float*)d_in[3];
    const float* Wms_w   = (const float*)d_in[4];
    const float* Wms_b   = (const float*)d_in[5];
    const float* Mw      = (const float*)d_in[6];
    const float* g       = (const float*)d_in[7];
    const float* Wrd_w   = (const float*)d_in[8];
    const float* Wrd_b   = (const float*)d_in[9];
    const float* bkeys   = (const float*)d_in[10];
    const float* bvals   = (const float*)d_in[11];
    const float* bused   = (const float*)d_in[12];

    float* y_out     = (float*)d_out;                       // [16384,1024]
    float* modes_out = y_out + (size_t)ROWS * DOUTD;        // [16384,256]

    char* w = (char*)d_ws;
    const size_t OFF_LOGITS = 0;                      // 16384*256*4  = 16,777,216
    const size_t OFF_MASKS  = 16777216;               // 16384*4*8    =    524,288
    const size_t OFF_CARR   = OFF_MASKS + 524288;     // 16384*4
    const size_t OFF_MODE   = OFF_CARR + 65536;       // 16384*4
    const size_t OFF_INVKN  = OFF_MODE + 65536;       // 4096*4
    const size_t OFF_SCORES = OFF_INVKN + 16384;      // 256*4096*4   =  4,194,304
    const size_t OFF_PART   = OFF_SCORES + 4194304;   // 8*256*512*4  =  4,194,304
    const size_t OFF_BANKO  = OFF_PART + 4194304;     // 256*512*4
    const size_t OFF_RN     = OFF_BANKO + 524288;     // 256*512*4
    const size_t OFF_YTAB   = OFF_RN + 524288;        // 256*1024*4
    const size_t OFF_H      = OFF_YTAB + 1048576;     // CH*2048*4

    float* logits = (float*)(w + OFF_LOGITS);
    unsigned long long* masks = (unsigned long long*)(w + OFF_MASKS);
    int*   cArr   = (int*)(w + OFF_CARR);
    int*   midx   = (int*)(w + OFF_MODE);
    float* invkn  = (float*)(w + OFF_INVKN);
    float* scores = (float*)(w + OFF_SCORES);
    float* part   = (float*)(w + OFF_PART);
    float* banko  = (float*)(w + OFF_BANKO);
    float* rn     = (float*)(w + OFF_RN);
    float* ytab   = (float*)(w + OFF_YTAB);
    float* hbuf   = (float*)(w + OFF_H);

    // ---- mode table pipeline (independent of the big GEMMs) ----
    invkn_k<<<BANKN, 64, 0, stream>>>(bkeys, invkn);
    // scores_raw[k,n] = M[k] . bank_keys[n]   (B^T GEMM: M=256,N=4096,K=512)
    gemm64<true, false><<<dim3(64, 4, 1), 256, 0, stream>>>(Mw, bkeys, nullptr, scores,
                                                            256, 4096, 512, 512);
    softmax_k<<<KDIM, 256, 0, stream>>>(Mw, invkn, bused, scores);
    // bank_out = attn @ bank_vals  (M=256,N=512,K=4096, split-K=8)
    gemm64<false, false><<<dim3(8, 4, 8), 256, 0, stream>>>(scores, bvals, nullptr, part,
                                                            256, 512, 4096, 512);
    redk_k<<<512, 256, 0, stream>>>(part, banko);
    rn_k<<<KDIM, 256, 0, stream>>>(Mw, banko, g, rn);
    // Ytab = rn @ Wrd_w + Wrd_b  (M=256,N=1024,K=512)
    gemm64<false, true><<<dim3(16, 4, 1), 256, 0, stream>>>(rn, Wrd_w, Wrd_b, ytab,
                                                            256, 1024, 512, 512);

    // ---- front GEMMs (fp32, vector ALU): h = relu(x@Wtr+b); logits = h@Wms+b ----
    const size_t needFull = OFF_H + (size_t)ROWS * HDIMD * 4;   // ~162 MB
    int CH = (ws_size >= needFull) ? ROWS : 2048;
    for (int ch0 = 0; ch0 < ROWS; ch0 += CH) {
        gemm128<true, true><<<dim3(HDIMD / 128, CH / 128), 256, 0, stream>>>(
            x + (size_t)ch0 * DIND, Wtr_w, Wtr_b, hbuf, CH, HDIMD, DIND);
        gemm128<false, true><<<dim3(KDIM / 128, CH / 128), 256, 0, stream>>>(
            hbuf, Wms_w, Wms_b, logits + (size_t)ch0 * KDIM, CH, KDIM, HDIMD);
    }

    // ---- mode selection ----
    topmask_k<<<ROWS, 64, 0, stream>>>(logits, masks, cArr);
    scan_k<<<1, 64, 0, stream>>>(masks, cArr, midx);

    // ---- outputs ----
    modesw_k<<<ROWS, 64, 0, stream>>>(midx, modes_out);
    ygather_k<<<ROWS, 256, 0, stream>>>(midx, ytab, y_out);
}

// Round 2
// 1028.151 us; speedup vs baseline: 1.5511x; 1.5511x over previous
//
#include <hip/hip_runtime.h>
#include <stdint.h>

#define ROWS   16384   // B*S
#define KDIM   256
#define DMDIM  512
#define DOUTD  1024
#define BANKN  4096
#define DIND   1024
#define HDIMD  2048
#define FPAD   1024    // max fixup rows

typedef unsigned int u32;
typedef unsigned long long u64;
typedef _Float16 v8h __attribute__((ext_vector_type(8)));
typedef short    v8s __attribute__((ext_vector_type(8)));
typedef float    v4f __attribute__((ext_vector_type(4)));

// ---------- split helpers: v = hi(f16) + lo(f16)*2^-11 ; lo stored pre-scaled by 2048 ----------
__device__ __forceinline__ u32 pack_split(float v) {
    _Float16 h = (_Float16)v;
    float r = (v - (float)h) * 2048.0f;     // exact scale; keeps lo in f16 normal range
    _Float16 l = (_Float16)r;
    unsigned short hs = __builtin_bit_cast(unsigned short, h);
    unsigned short ls = __builtin_bit_cast(unsigned short, l);
    return (u32)hs | ((u32)ls << 16);
}
__device__ __forceinline__ v8h unpL(uint4 a, uint4 b) {   // main (low 16 bits)
    v8s s1 = __builtin_bit_cast(v8s, a);
    v8s s2 = __builtin_bit_cast(v8s, b);
    v8s lo = __builtin_shufflevector(s1, s2, 0, 2, 4, 6, 8, 10, 12, 14);
    return __builtin_bit_cast(v8h, lo);
}
__device__ __forceinline__ v8h unpH(uint4 a, uint4 b) {   // scaled residual (high 16 bits)
    v8s s1 = __builtin_bit_cast(v8s, a);
    v8s s2 = __builtin_bit_cast(v8s, b);
    v8s hi = __builtin_shufflevector(s1, s2, 1, 3, 5, 7, 9, 11, 13, 15);
    return __builtin_bit_cast(v8h, hi);
}
__device__ __forceinline__ v4f mfma16(v8h a, v8h b, v4f c) {
    return __builtin_amdgcn_mfma_f32_16x16x32_f16(a, b, c, 0, 0, 0);
}
__device__ __forceinline__ void gl_lds16(const u32* g, u32* l) {
    __builtin_amdgcn_global_load_lds(g, l, 16, 0, 0);
}

// ---------------- split-f16 MFMA GEMM: C = A*B^T-packed, 128x128 tile, BK=32 ----------------
// A: [M x K] packed u32 (hi,lo). Bt: [N x K] packed u32. OSPLIT: relu+bias -> packed u32 out.
// else: fp32 partial out at Cv + bz*M*N (split-K via gridDim.z).
template<bool OSPLIT>
__global__ __launch_bounds__(256, 2)
void gemm_mfma(const u32* __restrict__ A, const u32* __restrict__ Bt,
               const float* __restrict__ bias, void* __restrict__ Cv,
               int K, int kLen)
{
    __shared__ u32 As[4096];   // 1024 chunks * 16B
    __shared__ u32 Bs[4096];
    const int N = gridDim.x * 128;
    const int M = gridDim.y * 128;

    // XCD-aware remap: blocks sharing an A-panel stay on one XCD
    long gx = gridDim.x, gy = gridDim.y, gz = gridDim.z;
    long flat = ((long)blockIdx.z * gy + blockIdx.y) * gx + blockIdx.x;
    long nb = gx * gy * gz;
    long lid = (flat & 7) * (nb >> 3) + (flat >> 3);
    int bx = (int)(lid % gx);
    long t2 = lid / gx;
    int by = (int)(t2 % gy);
    int bz = (int)(t2 / gy);

    const int m0 = by * 128, n0 = bx * 128;
    const int kStart = bz * kLen;

    const int tid = threadIdx.x;
    const int lane = tid & 63, wv = tid >> 6;
    const int lx = lane & 15, q = lane >> 4;
    const int wm = (wv >> 1) * 64, wn = (wv & 1) * 64;

    // staging source pointers (chunk c = r*256 + tid; row = (c>>6)*8 + (c&7), sub = (c>>3)&7)
    const u32* gA = A + (size_t)(m0 + (tid >> 6) * 8 + (tid & 7)) * K + kStart + ((tid >> 3) & 7) * 4;
    const u32* gB = Bt + (size_t)(n0 + (tid >> 6) * 8 + (tid & 7)) * K + kStart + ((tid >> 3) & 7) * 4;
    u32* lA = As + (wv * 64) * 4;
    u32* lB = Bs + (wv * 64) * 4;

    // fragment LDS offsets (u32 index); chunk = (m>>3)*64 + q*16 + (m&7)
    int caOff[4], cbOff[4];
    #pragma unroll
    for (int i = 0; i < 4; i++) {
        int m = wm + i * 16 + lx;
        caOff[i] = (((m >> 3) * 64) + q * 16 + (m & 7)) * 4;
        int n = wn + i * 16 + lx;
        cbOff[i] = (((n >> 3) * 64) + q * 16 + (n & 7)) * 4;
    }

    v4f acc1[4][4], acc2[4][4];
    #pragma unroll
    for (int i = 0; i < 4; i++)
        #pragma unroll
        for (int j = 0; j < 4; j++) { v4f z = {0.f, 0.f, 0.f, 0.f}; acc1[i][j] = z; acc2[i][j] = z; }

    for (int kt = 0; kt < kLen; kt += 32) {
        #pragma unroll
        for (int r = 0; r < 4; r++) {
            gl_lds16(gA + (size_t)r * 32 * K, lA + r * 1024);
            gl_lds16(gB + (size_t)r * 32 * K, lB + r * 1024);
        }
        gA += 32; gB += 32;
        __syncthreads();

        v8h am[4], ar[4], bm[4], br[4];
        #pragma unroll
        for (int i = 0; i < 4; i++) {
            uint4 x1 = *(const uint4*)(As + caOff[i]);
            uint4 x2 = *(const uint4*)(As + caOff[i] + 32);
            am[i] = unpL(x1, x2); ar[i] = unpH(x1, x2);
            uint4 y1 = *(const uint4*)(Bs + cbOff[i]);
            uint4 y2 = *(const uint4*)(Bs + cbOff[i] + 32);
            bm[i] = unpL(y1, y2); br[i] = unpH(y1, y2);
        }
        #pragma unroll
        for (int mi = 0; mi < 4; mi++)
            #pragma unroll
            for (int ni = 0; ni < 4; ni++) {
                acc1[mi][ni] = mfma16(am[mi], bm[ni], acc1[mi][ni]);
                acc2[mi][ni] = mfma16(am[mi], br[ni], acc2[mi][ni]);
                acc2[mi][ni] = mfma16(ar[mi], bm[ni], acc2[mi][ni]);
            }
        __syncthreads();
    }

    const float RS = 1.0f / 2048.0f;
    #pragma unroll
    for (int mi = 0; mi < 4; mi++) {
        #pragma unroll
        for (int ni = 0; ni < 4; ni++) {
            int col = n0 + wn + ni * 16 + lx;
            #pragma unroll
            for (int r = 0; r < 4; r++) {
                int row = m0 + wm + mi * 16 + q * 4 + r;
                float v = acc1[mi][ni][r] + acc2[mi][ni][r] * RS;
                if (OSPLIT) {
                    v += bias[col];
                    v = fmaxf(v, 0.f);
                    ((u32*)Cv)[(size_t)row * N + col] = pack_split(v);
                } else {
                    ((float*)Cv)[(size_t)bz * M * N + (size_t)row * N + col] = v;
                }
            }
        }
    }
}

// ---------------- elementwise split-pack of x ----------------
__global__ __launch_bounds__(256)
void splitx_k(const float* __restrict__ x, u32* __restrict__ xi, long n4)
{
    long i = (long)blockIdx.x * 256 + threadIdx.x;
    if (i >= n4) return;
    float4 v = ((const float4*)x)[i];
    uint4 o;
    o.x = pack_split(v.x); o.y = pack_split(v.y);
    o.z = pack_split(v.z); o.w = pack_split(v.w);
    ((uint4*)xi)[i] = o;
}

// ---------------- transpose + split-pack of weights: W[K x N] f32 -> Wt[N x K] u32 ----------------
__global__ __launch_bounds__(256)
void tsplit_k(const float* __restrict__ W, u32* __restrict__ Wt, int K, int N)
{
    __shared__ u32 L[32][33];
    int k0 = blockIdx.y * 32, n0 = blockIdx.x * 32;
    int r = threadIdx.x >> 3, c4 = (threadIdx.x & 7) * 4;
    float4 v = *(const float4*)(W + (size_t)(k0 + r) * N + n0 + c4);
    L[r][c4 + 0] = pack_split(v.x);
    L[r][c4 + 1] = pack_split(v.y);
    L[r][c4 + 2] = pack_split(v.z);
    L[r][c4 + 3] = pack_split(v.w);
    __syncthreads();
    uint4 ov;
    ov.x = L[c4 + 0][r]; ov.y = L[c4 + 1][r]; ov.z = L[c4 + 2][r]; ov.w = L[c4 + 3][r];
    *(uint4*)(Wt + (size_t)(n0 + r) * K + k0 + c4) = ov;
}

// ---------------- reduce split-K partials + bias -> logits ----------------
__global__ __launch_bounds__(256)
void reduce2_k(const float* __restrict__ part, const float* __restrict__ bias,
               float* __restrict__ outp, int total4, int zStride4)
{
    int i = blockIdx.x * 256 + threadIdx.x;
    if (i >= total4) return;
    const float4* p = (const float4*)part;
    float4 s = p[i];
    #pragma unroll
    for (int z = 1; z < 4; z++) {
        float4 t = p[(size_t)z * zStride4 + i];
        s.x += t.x; s.y += t.y; s.z += t.z; s.w += t.w;
    }
    float4 b = ((const float4*)bias)[i & 63];
    s.x += b.x; s.y += b.y; s.z += b.z; s.w += b.w;
    ((float4*)outp)[i] = s;
}

// ---------------- generic fp32 GEMM, 64x64 tile (table pipeline + fixup) ----------------
template<bool BT, bool BIAS, bool RELU>
__global__ __launch_bounds__(256)
void gemm64(const float* __restrict__ A, const float* __restrict__ Bm,
            const float* __restrict__ bias, float* __restrict__ C,
            int M, int N, int K, int kLen, const int* __restrict__ mcount)
{
    if (mcount && (int)blockIdx.y * 64 >= *mcount) return;
    __shared__ float As[16][68];
    __shared__ float Bs[16][68];
    const int tid = threadIdx.x;
    const int tx = tid & 15, ty = tid >> 4;
    const int m0 = blockIdx.y * 64;
    const int n0 = blockIdx.x * 64;
    const int z  = blockIdx.z;
    const int kStart = z * kLen;
    float* Cz = C + (size_t)z * M * N;
    float acc[4][4];
    #pragma unroll
    for (int i = 0; i < 4; i++)
        #pragma unroll
        for (int j = 0; j < 4; j++) acc[i][j] = 0.f;

    for (int kt = kStart; kt < kStart + kLen; kt += 16) {
        {
            int m = tid >> 2, kq = tid & 3;
            float4 av = *(const float4*)(A + (size_t)(m0 + m) * K + kt + kq * 4);
            As[kq*4+0][m]=av.x; As[kq*4+1][m]=av.y; As[kq*4+2][m]=av.z; As[kq*4+3][m]=av.w;
        }
        if (BT) {
            int n = tid >> 2, kq = tid & 3;
            float4 bv = *(const float4*)(Bm + (size_t)(n0 + n) * K + kt + kq * 4);
            Bs[kq*4+0][n]=bv.x; Bs[kq*4+1][n]=bv.y; Bs[kq*4+2][n]=bv.z; Bs[kq*4+3][n]=bv.w;
        } else {
            int n4 = tid & 15, kk = tid >> 4;
            float4 bv = *(const float4*)(Bm + (size_t)(kt + kk) * N + n0 + n4 * 4);
            *(float4*)&Bs[kk][n4 * 4] = bv;
        }
        __syncthreads();
        #pragma unroll
        for (int k = 0; k < 16; k++) {
            float4 a0 = *(const float4*)&As[k][ty * 4];
            float4 b0 = *(const float4*)&Bs[k][tx * 4];
            float a[4] = {a0.x, a0.y, a0.z, a0.w};
            float b[4] = {b0.x, b0.y, b0.z, b0.w};
            #pragma unroll
            for (int i = 0; i < 4; i++)
                #pragma unroll
                for (int j = 0; j < 4; j++)
                    acc[i][j] = fmaf(a[i], b[j], acc[i][j]);
        }
        __syncthreads();
    }
    float4 bi = make_float4(0.f,0.f,0.f,0.f);
    if (BIAS) bi = *(const float4*)(bias + n0 + tx * 4);
    #pragma unroll
    for (int i = 0; i < 4; i++) {
        int m = m0 + ty * 4 + i;
        float o0 = acc[i][0]+bi.x, o1 = acc[i][1]+bi.y, o2 = acc[i][2]+bi.z, o3 = acc[i][3]+bi.w;
        if (RELU) { o0=fmaxf(o0,0.f); o1=fmaxf(o1,0.f); o2=fmaxf(o2,0.f); o3=fmaxf(o3,0.f); }
        *(float4*)(Cz + (size_t)m * N + n0 + tx * 4) = make_float4(o0, o1, o2, o3);
    }
}

// ---------------- 1/max(||bank_keys[n]||,1e-12) ----------------
__global__ __launch_bounds__(64)
void invkn_k(const float* __restrict__ keys, float* __restrict__ inv_kn)
{
    int n = blockIdx.x, l = threadIdx.x;
    const float4* r = (const float4*)(keys + (size_t)n * 512);
    float4 a = r[l], b = r[l + 64];
    float s = a.x*a.x + a.y*a.y + a.z*a.z + a.w*a.w
            + b.x*b.x + b.y*b.y + b.z*b.z + b.w*b.w;
    #pragma unroll
    for (int off = 32; off; off >>= 1) s += __shfl_xor(s, off);
    if (l == 0) inv_kn[n] = 1.0f / fmaxf(sqrtf(s), 1e-12f);
}

// ---------------- masked scaled softmax over 4096 slots, per k-row, in place ----------------
__global__ __launch_bounds__(256)
void softmax_k(const float* __restrict__ Mw, const float* __restrict__ inv_kn,
               const float* __restrict__ used, float* __restrict__ sc)
{
    const int k = blockIdx.x, tid = threadIdx.x;
    __shared__ float red[256];
    float m0 = Mw[(size_t)k*512 + tid];
    float m1 = Mw[(size_t)k*512 + 256 + tid];
    red[tid] = m0*m0 + m1*m1;
    __syncthreads();
    for (int s = 128; s > 0; s >>= 1) { if (tid < s) red[tid] += red[tid+s]; __syncthreads(); }
    float scale = 4.0f / fmaxf(sqrtf(red[0]), 1e-12f);
    __syncthreads();
    float vals[16];
    float mx = -3.0e38f;
    #pragma unroll
    for (int j = 0; j < 16; j++) {
        int n = j*256 + tid;
        float v = sc[(size_t)k*4096 + n] * scale * inv_kn[n];
        v = (used[n] > 0.5f) ? v : -1e30f;
        vals[j] = v; mx = fmaxf(mx, v);
    }
    red[tid] = mx; __syncthreads();
    for (int s = 128; s > 0; s >>= 1) { if (tid < s) red[tid] = fmaxf(red[tid], red[tid+s]); __syncthreads(); }
    mx = red[0]; __syncthreads();
    float sum = 0.f;
    #pragma unroll
    for (int j = 0; j < 16; j++) { float e = expf(vals[j] - mx); vals[j] = e; sum += e; }
    red[tid] = sum; __syncthreads();
    for (int s = 128; s > 0; s >>= 1) { if (tid < s) red[tid] += red[tid+s]; __syncthreads(); }
    float inv = 1.0f / red[0];
    #pragma unroll
    for (int j = 0; j < 16; j++) { int n = j*256 + tid; sc[(size_t)k*4096 + n] = vals[j] * inv; }
}

// ---------------- reduce bank split-K partials ----------------
__global__ __launch_bounds__(256)
void redk_k(const float* __restrict__ part, float* __restrict__ outp)
{
    int idx = blockIdx.x * 256 + threadIdx.x;   // 131072 total
    float s = 0.f;
    #pragma unroll
    for (int z = 0; z < 8; z++) s += part[(size_t)z * 131072 + idx];
    outp[idx] = s;
}

// ---------------- rn table: RMS-norm of (M[k] + bank_out[k]) ----------------
__global__ __launch_bounds__(256)
void rn_k(const float* __restrict__ Mw, const float* __restrict__ banko,
          const float* __restrict__ g, float* __restrict__ rn)
{
    int k = blockIdx.x, tid = threadIdx.x;
    __shared__ float red[256];
    float r0 = Mw[(size_t)k*512 + tid]       + banko[(size_t)k*512 + tid];
    float r1 = Mw[(size_t)k*512 + 256 + tid] + banko[(size_t)k*512 + 256 + tid];
    red[tid] = r0*r0 + r1*r1;
    __syncthreads();
    for (int s = 128; s > 0; s >>= 1) { if (tid < s) red[tid] += red[tid+s]; __syncthreads(); }
    float denom = sqrtf(red[0] * (1.0f/512.0f) + 1e-6f);
    rn[(size_t)k*512 + tid]       = r0 * (g[tid] / denom);
    rn[(size_t)k*512 + 256 + tid] = r1 * (g[256 + tid] / denom);
}

// ---------------- per-row argmax (first-index ties) + sticky 256-bit mask ----------------
__global__ __launch_bounds__(64)
void topmask_k(const float* __restrict__ logits, u64* __restrict__ masks,
               int* __restrict__ cArr)
{
    int row = blockIdx.x, l = threadIdx.x;
    const float* lg = logits + (size_t)row * 256;
    float v0 = lg[l], v1 = lg[64 + l], v2 = lg[128 + l], v3 = lg[192 + l];
    float bv = v0; int bp = l;
    if (v1 > bv) { bv = v1; bp = 64 + l; }
    if (v2 > bv) { bv = v2; bp = 128 + l; }
    if (v3 > bv) { bv = v3; bp = 192 + l; }
    #pragma unroll
    for (int off = 32; off; off >>= 1) {
        float ov = __shfl_xor(bv, off);
        int   op = __shfl_xor(bp, off);
        if (ov > bv || (ov == bv && op < bp)) { bv = ov; bp = op; }
    }
    float t0 = v0 + 0.1f, t1 = v1 + 0.1f, t2 = v2 + 0.1f, t3 = v3 + 0.1f;
    u64 w0 = __ballot((t0 > bv) || (t0 == bv && (l)       < bp));
    u64 w1 = __ballot((t1 > bv) || (t1 == bv && (64 + l)  < bp));
    u64 w2 = __ballot((t2 > bv) || (t2 == bv && (128 + l) < bp));
    u64 w3 = __ballot((t3 > bv) || (t3 == bv && (192 + l) < bp));
    if (l == 0) {
        masks[(size_t)row*4 + 0] = w0;
        masks[(size_t)row*4 + 1] = w1;
        masks[(size_t)row*4 + 2] = w2;
        masks[(size_t)row*4 + 3] = w3;
        cArr[row] = bp;
    }
}

// ---------------- flag rows with risky (small) decision margins ----------------
__global__ __launch_bounds__(64)
void flag_k(const float* __restrict__ logits, int* __restrict__ flags)
{
    int row = blockIdx.x, l = threadIdx.x;
    const float* lg = logits + (size_t)row * 256;
    float v0 = lg[l], v1 = lg[64 + l], v2 = lg[128 + l], v3 = lg[192 + l];
    float bv = v0; int bp = l;
    if (v1 > bv) { bv = v1; bp = 64 + l; }
    if (v2 > bv) { bv = v2; bp = 128 + l; }
    if (v3 > bv) { bv = v3; bp = 192 + l; }
    #pragma unroll
    for (int off = 32; off; off >>= 1) {
        float ov = __shfl_xor(bv, off);
        int   op = __shfl_xor(bp, off);
        if (ov > bv || (ov == bv && op < bp)) { bv = ov; bp = op; }
    }
    const float D = 1e-3f;
    bool r = false;
    r |= (v0 > bv - D) && ((l)       != bp);  r |= fabsf(v0 + 0.1f - bv) < D;
    r |= (v1 > bv - D) && ((64 + l)  != bp);  r |= fabsf(v1 + 0.1f - bv) < D;
    r |= (v2 > bv - D) && ((128 + l) != bp);  r |= fabsf(v2 + 0.1f - bv) < D;
    r |= (v3 > bv - D) && ((192 + l) != bp);  r |= fabsf(v3 + 0.1f - bv) < D;
    u64 any = __ballot(r);
    if (l == 0) flags[row] = (any != 0ULL) ? 1 : 0;
}

__global__ __launch_bounds__(256)
void compact_k(const int* __restrict__ flags, int* __restrict__ ridx, int* __restrict__ cnt)
{
    int row = blockIdx.x * 256 + threadIdx.x;
    if (row >= ROWS) return;
    if (flags[row]) {
        int p = atomicAdd(cnt, 1);
        if (p < FPAD) ridx[p] = row;
    }
}

__global__ __launch_bounds__(256)
void gatherx_k(const float* __restrict__ x, const int* __restrict__ ridx,
               const int* __restrict__ cnt, float* __restrict__ xg)
{
    int b = blockIdx.x;
    int n = *cnt; if (n > FPAD) n = FPAD;
    if (b >= n) return;
    int row = ridx[b];
    ((float4*)(xg + (size_t)b * 1024))[threadIdx.x] =
        ((const float4*)(x + (size_t)row * 1024))[threadIdx.x];
}

__global__ __launch_bounds__(64)
void scatterlg_k(const float* __restrict__ lgg, const int* __restrict__ ridx,
                 const int* __restrict__ cnt, float* __restrict__ logits)
{
    int b = blockIdx.x;
    int n = *cnt; if (n > FPAD) n = FPAD;
    if (b >= n) return;
    int row = ridx[b];
    ((float4*)(logits + (size_t)row * 256))[threadIdx.x] =
        ((const float4*)(lgg + (size_t)b * 256))[threadIdx.x];
}

// ---------------- fast sequential scan: 8 chains, register-resident via readlane ----------------
__global__ __launch_bounds__(64)
void scan2_k(const u64* __restrict__ masks, const int* __restrict__ cArr,
             const float* __restrict__ prev_mode, int* __restrict__ midx)
{
    int b = blockIdx.x, l = threadIdx.x;
    // initial prev from prev_mode one-hot row
    float4 pm = ((const float4*)(prev_mode + (size_t)b * 256))[l];
    int my = -1;
    if (pm.x > 0.5f) my = l * 4 + 0;
    if (pm.y > 0.5f) my = l * 4 + 1;
    if (pm.z > 0.5f) my = l * 4 + 2;
    if (pm.w > 0.5f) my = l * 4 + 3;
    u64 bal = __ballot(my >= 0);
    int prev = 0;
    if (bal) {
        int src = __ffsll(bal) - 1;
        prev = __builtin_amdgcn_readlane(my, src);
    }

    const int base = b * 2048;
    ulonglong2 nx01 = *(const ulonglong2*)(masks + (size_t)(base + l) * 4);
    ulonglong2 nx23 = *(const ulonglong2*)(masks + (size_t)(base + l) * 4 + 2);
    int nxc = cArr[base + l];

    for (int seg = 0; seg < 32; ++seg) {
        ulonglong2 c01 = nx01, c23 = nx23;
        int cc = nxc;
        if (seg < 31) {
            int row = base + (seg + 1) * 64 + l;
            nx01 = *(const ulonglong2*)(masks + (size_t)row * 4);
            nx23 = *(const ulonglong2*)(masks + (size_t)row * 4 + 2);
            nxc = cArr[row];
        }
        int myres = 0;
        for (int j = 0; j < 64; ++j) {
            u64 wlo = (prev & 64) ? c01.y : c01.x;
            u64 whi = (prev & 64) ? c23.y : c23.x;
            u64 w   = (prev & 128) ? whi : wlo;
            unsigned int lo32 = (unsigned int)__builtin_amdgcn_readlane((int)(unsigned int)w, j);
            unsigned int hi32 = (unsigned int)__builtin_amdgcn_readlane((int)(unsigned int)(w >> 32), j);
            int c = __builtin_amdgcn_readlane(cc, j);
            u64 ww = ((u64)hi32 << 32) | (u64)lo32;
            int stick = (int)((ww >> (prev & 63)) & 1ULL);
            prev = stick ? prev : c;
            myres = (l == j) ? prev : myres;
        }
        midx[base + seg * 64 + l] = myres;
    }
}

// ---------------- modes one-hot output ----------------
__global__ __launch_bounds__(64)
void modesw_k(const int* __restrict__ mode_idx, float* __restrict__ modes)
{
    int r = blockIdx.x, l = threadIdx.x;
    int k = mode_idx[r];
    int base = l * 4;
    float4 v = make_float4(base == k ? 1.f : 0.f, base+1 == k ? 1.f : 0.f,
                           base+2 == k ? 1.f : 0.f, base+3 == k ? 1.f : 0.f);
    ((float4*)(modes + (size_t)r * 256))[l] = v;
}

// ---------------- y gather from 256-entry table ----------------
__global__ __launch_bounds__(256)
void ygather_k(const int* __restrict__ mode_idx, const float* __restrict__ ytab,
               float* __restrict__ y)
{
    int r = blockIdx.x;
    int k = mode_idx[r];
    const float4* src = (const float4*)(ytab + (size_t)k * 1024);
    float4* dst = (float4*)(y + (size_t)r * 1024);
    dst[threadIdx.x] = src[threadIdx.x];
}

extern "C" void kernel_launch(void* const* d_in, const int* in_sizes, int n_in,
                              void* d_out, int out_size, void* d_ws, size_t ws_size,
                              hipStream_t stream)
{
    const float* x       = (const float*)d_in[0];
    const float* prevm   = (const float*)d_in[1];
    const float* Wtr_w   = (const float*)d_in[2];
    const float* Wtr_b   = (const float*)d_in[3];
    const float* Wms_w   = (const float*)d_in[4];
    const float* Wms_b   = (const float*)d_in[5];
    const float* Mw      = (const float*)d_in[6];
    const float* g       = (const float*)d_in[7];
    const float* Wrd_w   = (const float*)d_in[8];
    const float* Wrd_b   = (const float*)d_in[9];
    const float* bkeys   = (const float*)d_in[10];
    const float* bvals   = (const float*)d_in[11];
    const float* bused   = (const float*)d_in[12];

    float* y_out     = (float*)d_out;                       // [16384,1024]
    float* modes_out = y_out + (size_t)ROWS * DOUTD;        // [16384,256]

    char* w = (char*)d_ws;
    size_t o = 0;
    auto alloc = [&](size_t b) { size_t r = o; o = (o + b + 255) & ~(size_t)255; return r; };

    size_t oLog  = alloc((size_t)ROWS * 256 * 4);
    size_t oMask = alloc((size_t)ROWS * 32);
    size_t oCar  = alloc((size_t)ROWS * 4);
    size_t oMidx = alloc((size_t)ROWS * 4);
    size_t oInv  = alloc((size_t)BANKN * 4);
    size_t oSc   = alloc((size_t)256 * 4096 * 4);
    size_t oPB   = alloc((size_t)8 * 256 * 512 * 4);
    size_t oBo   = alloc((size_t)256 * 512 * 4);
    size_t oRn   = alloc((size_t)256 * 512 * 4);
    size_t oYt   = alloc((size_t)256 * 1024 * 4);
    size_t oW1   = alloc((size_t)HDIMD * DIND * 4);   // WtrT packed [2048 x 1024]
    size_t oW2   = alloc((size_t)KDIM * HDIMD * 4);   // WmsT packed [256 x 2048]
    size_t oFlag = alloc((size_t)ROWS * 4);
    size_t oRidx = alloc((size_t)FPAD * 4);
    size_t oCnt  = alloc(256);
    size_t oXg   = alloc((size_t)FPAD * DIND * 4);
    size_t oHg   = alloc((size_t)FPAD * HDIMD * 4);
    size_t oLgg  = alloc((size_t)FPAD * 256 * 4);
    size_t persist = o;

    int CM = 256;
    const int cands[7] = {16384, 8192, 4096, 2048, 1024, 512, 256};
    for (int i = 0; i < 7; i++) {
        size_t need = persist + (size_t)cands[i] * 16384 + 1024;
        if (need <= ws_size) { CM = cands[i]; break; }
    }
    size_t oXi = alloc((size_t)CM * DIND * 4);
    size_t oHi = alloc((size_t)CM * HDIMD * 4);
    size_t oP2 = alloc((size_t)4 * CM * 256 * 4);

    float* logits = (float*)(w + oLog);
    u64*   masks  = (u64*)(w + oMask);
    int*   cArr   = (int*)(w + oCar);
    int*   midx   = (int*)(w + oMidx);
    float* invkn  = (float*)(w + oInv);
    float* scores = (float*)(w + oSc);
    float* partB  = (float*)(w + oPB);
    float* banko  = (float*)(w + oBo);
    float* rn     = (float*)(w + oRn);
    float* ytab   = (float*)(w + oYt);
    u32*   W1t    = (u32*)(w + oW1);
    u32*   W2t    = (u32*)(w + oW2);
    int*   flags  = (int*)(w + oFlag);
    int*   ridx   = (int*)(w + oRidx);
    int*   cnt    = (int*)(w + oCnt);
    float* xg     = (float*)(w + oXg);
    float* hg     = (float*)(w + oHg);
    float* lgg    = (float*)(w + oLgg);
    u32*   xi     = (u32*)(w + oXi);
    u32*   hi     = (u32*)(w + oHi);
    float* part2  = (float*)(w + oP2);

    // ---- mode table pipeline (fp32, independent of front GEMMs) ----
    invkn_k<<<BANKN, 64, 0, stream>>>(bkeys, invkn);
    gemm64<true, false, false><<<dim3(64, 4, 1), 256, 0, stream>>>(Mw, bkeys, nullptr, scores,
                                                                   256, 4096, 512, 512, nullptr);
    softmax_k<<<KDIM, 256, 0, stream>>>(Mw, invkn, bused, scores);
    gemm64<false, false, false><<<dim3(8, 4, 8), 256, 0, stream>>>(scores, bvals, nullptr, partB,
                                                                   256, 512, 4096, 512, nullptr);
    redk_k<<<512, 256, 0, stream>>>(partB, banko);
    rn_k<<<KDIM, 256, 0, stream>>>(Mw, banko, g, rn);
    gemm64<false, true, false><<<dim3(16, 4, 1), 256, 0, stream>>>(rn, Wrd_w, Wrd_b, ytab,
                                                                   256, 1024, 512, 512, nullptr);

    // ---- weight split+transpose ----
    tsplit_k<<<dim3(HDIMD / 32, DIND / 32), 256, 0, stream>>>(Wtr_w, W1t, DIND, HDIMD);
    tsplit_k<<<dim3(KDIM / 32, HDIMD / 32), 256, 0, stream>>>(Wms_w, W2t, HDIMD, KDIM);

    // ---- front GEMMs via split-f16 MFMA ----
    for (int ch0 = 0; ch0 < ROWS; ch0 += CM) {
        long n4 = (long)CM * DIND / 4;
        splitx_k<<<(int)((n4 + 255) / 256), 256, 0, stream>>>(x + (size_t)ch0 * DIND, xi, n4);
        // h = relu(x@Wtr + b), packed split out
        gemm_mfma<true><<<dim3(HDIMD / 128, CM / 128, 1), 256, 0, stream>>>(
            xi, W1t, Wtr_b, hi, DIND, DIND);
        // logits partials = h@Wms (split-K = 4)
        gemm_mfma<false><<<dim3(KDIM / 128, CM / 128, 4), 256, 0, stream>>>(
            hi, W2t, nullptr, part2, HDIMD, HDIMD / 4);
        int total4 = CM * 256 / 4;
        reduce2_k<<<(total4 + 255) / 256, 256, 0, stream>>>(part2, Wms_b,
            logits + (size_t)ch0 * 256, total4, total4);
    }

    // ---- fixup: recompute risky rows in exact fp32 ----
    flag_k<<<ROWS, 64, 0, stream>>>(logits, flags);
    hipMemsetAsync(cnt, 0, 4, stream);
    compact_k<<<ROWS / 256, 256, 0, stream>>>(flags, ridx, cnt);
    gatherx_k<<<FPAD, 256, 0, stream>>>(x, ridx, cnt, xg);
    gemm64<false, true, true><<<dim3(HDIMD / 64, FPAD / 64, 1), 256, 0, stream>>>(
        xg, Wtr_w, Wtr_b, hg, FPAD, HDIMD, DIND, DIND, cnt);
    gemm64<false, true, false><<<dim3(256 / 64, FPAD / 64, 1), 256, 0, stream>>>(
        hg, Wms_w, Wms_b, lgg, FPAD, 256, HDIMD, HDIMD, cnt);
    scatterlg_k<<<FPAD, 64, 0, stream>>>(lgg, ridx, cnt, logits);

    // ---- mode selection ----
    topmask_k<<<ROWS, 64, 0, stream>>>(logits, masks, cArr);
    scan2_k<<<8, 64, 0, stream>>>(masks, cArr, prevm, midx);

    // ---- outputs ----
    modesw_k<<<ROWS, 64, 0, stream>>>(midx, modes_out);
    ygather_k<<<ROWS, 256, 0, stream>>>(midx, ytab, y_out);
}